// Round 1
// baseline (2040.995 us; speedup 1.0000x reference)
//
#include <hip/hip_runtime.h>
#include <math.h>

#define B 16
#define C 384
#define H 96
#define W 96
#define HW (H*W)
#define M 2048
#define K2 49
#define RAD 3
#define NSEL 512
#define INV_TAU 10.0f

__device__ inline float wave_max(float v){
  #pragma unroll
  for (int o = 32; o; o >>= 1) v = fmaxf(v, __shfl_xor(v, o));
  return v;
}
__device__ inline float wave_sum(float v){
  #pragma unroll
  for (int o = 32; o; o >>= 1) v += __shfl_xor(v, o);
  return v;
}

// K1: per-pixel inverse L2 norms over channels, both tensors in one pass.
__global__ void norms_kernel(const float* __restrict__ t, const float* __restrict__ s,
                             float* __restrict__ inv_t, float* __restrict__ inv_s){
  int pix = blockIdx.x * blockDim.x + threadIdx.x;
  if (pix >= B * HW) return;
  int b = pix / HW, p = pix - b * HW;
  const float* tb = t + (size_t)b * C * HW + p;
  const float* sb = s + (size_t)b * C * HW + p;
  float at = 0.f, as = 0.f;
  #pragma unroll 4
  for (int c = 0; c < C; ++c){
    float v = tb[(size_t)c * HW]; at = fmaf(v, v, at);
    float u = sb[(size_t)c * HW]; as = fmaf(u, u, as);
  }
  inv_t[pix] = 1.0f / fmaxf(sqrtf(at), 1e-12f);
  inv_s[pix] = 1.0f / fmaxf(sqrtf(as), 1e-12f);
}

// K2: one wave per (b, candidate). Lane k (<49) accumulates dot(center, neigh_k)
// over C on the raw teacher; normalize with cached inv-norms; softmax+entropy
// via wave shuffles. sims cached to ws for reuse as sim_t in the KL phase.
__global__ void cand_kernel(const float* __restrict__ t, const int* __restrict__ anch,
                            const float* __restrict__ inv_t,
                            float* __restrict__ simc, float* __restrict__ ent){
  int bm = blockIdx.x;
  int b = bm >> 11, m = bm & (M - 1);
  int lane = threadIdx.x;
  int ay = anch[2 * m], ax = anch[2 * m + 1];
  int k = lane < K2 ? lane : 0;
  int dy = k / 7 - RAD, dx = k - (k / 7) * 7 - RAD;
  int pc = ay * W + ax;
  int pk = (ay + dy) * W + (ax + dx);
  const float* base = t + (size_t)b * C * HW;
  float acc = 0.f;
  #pragma unroll 4
  for (int c = 0; c < C; ++c){
    const float* row = base + (size_t)c * HW;
    acc = fmaf(row[pc], row[pk], acc);
  }
  float sim = acc * inv_t[b * HW + pc] * inv_t[b * HW + pk] * INV_TAU;
  float v = (lane < K2) ? sim : -INFINITY;
  float mx = wave_max(v);
  float e = (lane < K2) ? expf(sim - mx) : 0.f;
  float se = wave_sum(e);
  float p = e / se;
  float term = (lane < K2) ? (-p * logf(p + 1e-6f)) : 0.f;
  float en = wave_sum(term);
  if (lane == 0) ent[bm] = en;
  if (lane < K2) simc[(size_t)bm * K2 + lane] = sim;
}

// K3: exact top-512-smallest-entropy selection per image via rank counting.
// rank = #{j : (ent_j, j) < (ent_i, i)} lexicographic == jax.lax.top_k(-ent)
// tie-breaking (ties -> lowest index). Ranks are unique so sel is a perfect
// compaction. Also zeroes the output accumulator (runs before kl_kernel).
__global__ void select_kernel(const float* __restrict__ ent, int* __restrict__ sel,
                              float* __restrict__ out){
  int blk = blockIdx.x;                 // B*8 blocks
  int b = blk >> 3;
  int i = (blk & 7) * 256 + threadIdx.x;
  __shared__ float se[M];
  for (int j = threadIdx.x; j < M; j += 256) se[j] = ent[b * M + j];
  __syncthreads();
  if (blk == 0 && threadIdx.x == 0) out[0] = 0.f;
  float ei = se[i];
  int r = 0;
  for (int j = 0; j < M; ++j){
    float ej = se[j];
    r += (ej < ei) || (ej == ei && j < i);
  }
  if (r < NSEL) sel[b * NSEL + r] = i;
}

// K4: one wave per (b, selected anchor). Student sims gathered fresh;
// teacher sims read back from simc. Dual log-softmax + KL via wave shuffles.
__global__ void kl_kernel(const float* __restrict__ s, const int* __restrict__ anch,
                          const float* __restrict__ inv_s, const float* __restrict__ simc,
                          const int* __restrict__ sel, float* __restrict__ out){
  int bj = blockIdx.x;
  int b = bj >> 9, j = bj & (NSEL - 1);
  int lane = threadIdx.x;
  int m = sel[b * NSEL + j];
  int ay = anch[2 * m], ax = anch[2 * m + 1];
  int k = lane < K2 ? lane : 0;
  int dy = k / 7 - RAD, dx = k - (k / 7) * 7 - RAD;
  int pc = ay * W + ax;
  int pk = (ay + dy) * W + (ax + dx);
  const float* base = s + (size_t)b * C * HW;
  float acc = 0.f;
  #pragma unroll 4
  for (int c = 0; c < C; ++c){
    const float* row = base + (size_t)c * HW;
    acc = fmaf(row[pc], row[pk], acc);
  }
  float sim_sv = acc * inv_s[b * HW + pc] * inv_s[b * HW + pk] * INV_TAU;
  float sim_tv = (lane < K2) ? simc[((size_t)b * M + m) * K2 + lane] : -INFINITY;

  float vs = (lane < K2) ? sim_sv : -INFINITY;
  float mxs = wave_max(vs);
  float es = (lane < K2) ? expf(sim_sv - mxs) : 0.f;
  float sums = wave_sum(es);
  float ls = sim_sv - mxs - logf(sums);

  float mxt = wave_max(sim_tv);
  float et = (lane < K2) ? expf(sim_tv - mxt) : 0.f;
  float sumt = wave_sum(et);
  float lt = sim_tv - mxt - logf(sumt);

  float pt = et / sumt;                       // == exp(lt)
  float term = (lane < K2) ? pt * (lt - ls) : 0.f;
  float kl = wave_sum(term);
  if (lane == 0) atomicAdd(out, kl * (1.0f / (B * NSEL)));
}

extern "C" void kernel_launch(void* const* d_in, const int* in_sizes, int n_in,
                              void* d_out, int out_size, void* d_ws, size_t ws_size,
                              hipStream_t stream){
  const float* student = (const float*)d_in[0];
  const float* teacher = (const float*)d_in[1];
  const int*   anch    = (const int*)d_in[2];
  float* out = (float*)d_out;

  float* ws    = (float*)d_ws;
  float* inv_t = ws;                                  // B*HW
  float* inv_s = inv_t + B * HW;                      // B*HW
  float* ent   = inv_s + B * HW;                      // B*M
  float* simc  = ent + B * M;                         // B*M*K2
  int*   sel   = (int*)(simc + (size_t)B * M * K2);   // B*NSEL

  hipLaunchKernelGGL(norms_kernel, dim3((B * HW + 255) / 256), dim3(256), 0, stream,
                     teacher, student, inv_t, inv_s);
  hipLaunchKernelGGL(cand_kernel, dim3(B * M), dim3(64), 0, stream,
                     teacher, anch, inv_t, simc, ent);
  hipLaunchKernelGGL(select_kernel, dim3(B * 8), dim3(256), 0, stream,
                     ent, sel, out);
  hipLaunchKernelGGL(kl_kernel, dim3(B * NSEL), dim3(64), 0, stream,
                     student, anch, inv_s, simc, sel, out);
}

// Round 3
// 980.554 us; speedup vs baseline: 2.0815x; 2.0815x over previous
//
#include <hip/hip_runtime.h>
#include <math.h>

#define B 16
#define C 384
#define CPAD 385
#define H 96
#define W 96
#define HW (H*W)
#define M 2048
#define K2 49
#define RAD 3
#define NSEL 512
#define INV_TAU 10.0f
#define TP 32            // pixels per transpose tile

__device__ inline float wave_max(float v){
  #pragma unroll
  for (int o = 32; o; o >>= 1) v = fmaxf(v, __shfl_xor(v, o));
  return v;
}
__device__ inline float wave_sum(float v){
  #pragma unroll
  for (int o = 32; o; o >>= 1) v += __shfl_xor(v, o);
  return v;
}

// ---------------- fast path: pixel-major layout ----------------

// Transpose [C, HW-tile] -> [pix, C], normalizing each pixel's channel vector.
__global__ void tnorm_kernel(const float* __restrict__ src, float* __restrict__ dst){
  int blk = blockIdx.x;                 // B * (HW/TP)
  int b = blk / (HW / TP);
  int pixbase = (blk % (HW / TP)) * TP;
  __shared__ float tile[TP][CPAD];      // +1 pad: conflict-free col writes
  __shared__ float scale[TP];
  const float* sb = src + (size_t)b * C * HW + pixbase;
  int tx = threadIdx.x & 31;            // pixel in tile
  int ty = threadIdx.x >> 5;            // channel slice 0..7
  #pragma unroll 4
  for (int c0 = 0; c0 < C; c0 += 8){
    tile[tx][c0 + ty] = sb[(size_t)(c0 + ty) * HW + tx];
  }
  __syncthreads();
  // per-pixel sum of squares: 8 consecutive lanes per pixel
  int pix = threadIdx.x >> 3;
  int j = threadIdx.x & 7;
  float ss = 0.f;
  #pragma unroll 4
  for (int c = j * 48; c < j * 48 + 48; ++c){ float v = tile[pix][c]; ss = fmaf(v, v, ss); }
  ss += __shfl_xor(ss, 1); ss += __shfl_xor(ss, 2); ss += __shfl_xor(ss, 4);
  if (j == 0) scale[pix] = 1.0f / fmaxf(sqrtf(ss), 1e-12f);
  __syncthreads();
  float* db = dst + ((size_t)b * HW + pixbase) * C;
  #pragma unroll 4
  for (int l = threadIdx.x; l < TP * C; l += 256){
    int p = l / C, c = l - p * C;
    db[(size_t)p * C + c] = tile[p][c] * scale[p];
  }
}

// One wave per (b, candidate): 49 length-384 dots on contiguous normalized
// vectors; softmax+entropy via shuffles; sims cached for the KL phase.
__global__ void cand2_kernel(const float* __restrict__ fT, const int* __restrict__ anch,
                             float* __restrict__ simc, float* __restrict__ ent){
  int bm = blockIdx.x;
  int b = bm >> 11, m = bm & (M - 1);
  int lane = threadIdx.x;
  int ay = anch[2 * m], ax = anch[2 * m + 1];
  const float* img = fT + (size_t)b * HW * C;
  const float* ctr = img + (size_t)(ay * W + ax) * C + lane * 6;
  float c0 = ctr[0], c1 = ctr[1], c2 = ctr[2], c3 = ctr[3], c4 = ctr[4], c5 = ctr[5];
  float mysim = 0.f;
  int k = 0;
  for (int dy = -RAD; dy <= RAD; ++dy){
    #pragma unroll
    for (int dx = -RAD; dx <= RAD; ++dx){
      const float* nb = img + (size_t)((ay + dy) * W + (ax + dx)) * C + lane * 6;
      float acc = c0 * nb[0];
      acc = fmaf(c1, nb[1], acc); acc = fmaf(c2, nb[2], acc);
      acc = fmaf(c3, nb[3], acc); acc = fmaf(c4, nb[4], acc);
      acc = fmaf(c5, nb[5], acc);
      acc += __shfl_xor(acc, 32); acc += __shfl_xor(acc, 16);
      acc += __shfl_xor(acc, 8);  acc += __shfl_xor(acc, 4);
      acc += __shfl_xor(acc, 2);  acc += __shfl_xor(acc, 1);
      if (lane == k) mysim = acc;
      ++k;
    }
  }
  mysim *= INV_TAU;
  float v = (lane < K2) ? mysim : -INFINITY;
  float mx = wave_max(v);
  float e = (lane < K2) ? expf(mysim - mx) : 0.f;
  float se = wave_sum(e);
  float p = e / se;
  float term = (lane < K2) ? (-p * logf(p + 1e-6f)) : 0.f;
  float en = wave_sum(term);
  if (lane == 0) ent[bm] = en;
  if (lane < K2) simc[(size_t)bm * K2 + lane] = mysim;
}

// Exact top-512-smallest-entropy per image via lexicographic rank counting
// (matches jax.lax.top_k tie-breaking; ranks unique -> perfect compaction).
__global__ void select_kernel(const float* __restrict__ ent, int* __restrict__ sel){
  int blk = blockIdx.x;                 // B*8 blocks
  int b = blk >> 3;
  int i = (blk & 7) * 256 + threadIdx.x;
  __shared__ float se[M];
  for (int j = threadIdx.x; j < M; j += 256) se[j] = ent[b * M + j];
  __syncthreads();
  float ei = se[i];
  int r = 0;
  for (int j = 0; j < M; ++j){
    float ej = se[j];
    r += (ej < ei) || (ej == ei && j < i);
  }
  if (r < NSEL) sel[b * NSEL + r] = i;
}

// One wave per (b, selected anchor): student sims from normalized pixel-major
// student; teacher sims from cache; dual log-softmax + KL; per-wave partial.
__global__ void kl2_kernel(const float* __restrict__ fS, const int* __restrict__ anch,
                           const float* __restrict__ simc, const int* __restrict__ sel,
                           float* __restrict__ klpart){
  int bj = blockIdx.x;
  int b = bj >> 9, j = bj & (NSEL - 1);
  int lane = threadIdx.x;
  int m = sel[b * NSEL + j];
  int ay = anch[2 * m], ax = anch[2 * m + 1];
  const float* img = fS + (size_t)b * HW * C;
  const float* ctr = img + (size_t)(ay * W + ax) * C + lane * 6;
  float c0 = ctr[0], c1 = ctr[1], c2 = ctr[2], c3 = ctr[3], c4 = ctr[4], c5 = ctr[5];
  float mysim = 0.f;
  int k = 0;
  for (int dy = -RAD; dy <= RAD; ++dy){
    #pragma unroll
    for (int dx = -RAD; dx <= RAD; ++dx){
      const float* nb = img + (size_t)((ay + dy) * W + (ax + dx)) * C + lane * 6;
      float acc = c0 * nb[0];
      acc = fmaf(c1, nb[1], acc); acc = fmaf(c2, nb[2], acc);
      acc = fmaf(c3, nb[3], acc); acc = fmaf(c4, nb[4], acc);
      acc = fmaf(c5, nb[5], acc);
      acc += __shfl_xor(acc, 32); acc += __shfl_xor(acc, 16);
      acc += __shfl_xor(acc, 8);  acc += __shfl_xor(acc, 4);
      acc += __shfl_xor(acc, 2);  acc += __shfl_xor(acc, 1);
      if (lane == k) mysim = acc;
      ++k;
    }
  }
  float sim_sv = mysim * INV_TAU;
  float sim_tv = (lane < K2) ? simc[((size_t)b * M + m) * K2 + lane] : -INFINITY;

  float vs = (lane < K2) ? sim_sv : -INFINITY;
  float mxs = wave_max(vs);
  float es = (lane < K2) ? expf(sim_sv - mxs) : 0.f;
  float sums = wave_sum(es);
  float ls = sim_sv - mxs - logf(sums);

  float mxt = wave_max(sim_tv);
  float et = (lane < K2) ? expf(sim_tv - mxt) : 0.f;
  float sumt = wave_sum(et);
  float lt = sim_tv - mxt - logf(sumt);

  float pt = et / sumt;
  float term = (lane < K2) ? pt * (lt - ls) : 0.f;
  float kl = wave_sum(term);
  if (lane == 0) klpart[bj] = kl;
}

__global__ void reduce_kernel(const float* __restrict__ part, float* __restrict__ out){
  float s = 0.f;
  for (int i = threadIdx.x; i < B * NSEL; i += 256) s += part[i];
  s = wave_sum(s);
  __shared__ float wsum[4];
  if ((threadIdx.x & 63) == 0) wsum[threadIdx.x >> 6] = s;
  __syncthreads();
  if (threadIdx.x == 0) out[0] = (wsum[0] + wsum[1] + wsum[2] + wsum[3]) * (1.0f / (B * NSEL));
}

// ---------------- fallback path (round-1, ~13 MB ws) ----------------

__global__ void norms_kernel(const float* __restrict__ t, const float* __restrict__ s,
                             float* __restrict__ inv_t, float* __restrict__ inv_s){
  int pix = blockIdx.x * blockDim.x + threadIdx.x;
  if (pix >= B * HW) return;
  int b = pix / HW, p = pix - b * HW;
  const float* tb = t + (size_t)b * C * HW + p;
  const float* sb = s + (size_t)b * C * HW + p;
  float at = 0.f, as = 0.f;
  #pragma unroll 4
  for (int c = 0; c < C; ++c){
    float v = tb[(size_t)c * HW]; at = fmaf(v, v, at);
    float u = sb[(size_t)c * HW]; as = fmaf(u, u, as);
  }
  inv_t[pix] = 1.0f / fmaxf(sqrtf(at), 1e-12f);
  inv_s[pix] = 1.0f / fmaxf(sqrtf(as), 1e-12f);
}

__global__ void cand_kernel(const float* __restrict__ t, const int* __restrict__ anch,
                            const float* __restrict__ inv_t,
                            float* __restrict__ simc, float* __restrict__ ent){
  int bm = blockIdx.x;
  int b = bm >> 11, m = bm & (M - 1);
  int lane = threadIdx.x;
  int ay = anch[2 * m], ax = anch[2 * m + 1];
  int k = lane < K2 ? lane : 0;
  int dy = k / 7 - RAD, dx = k - (k / 7) * 7 - RAD;
  int pc = ay * W + ax;
  int pk = (ay + dy) * W + (ax + dx);
  const float* base = t + (size_t)b * C * HW;
  float acc = 0.f;
  #pragma unroll 4
  for (int c = 0; c < C; ++c){
    const float* row = base + (size_t)c * HW;
    acc = fmaf(row[pc], row[pk], acc);
  }
  float sim = acc * inv_t[b * HW + pc] * inv_t[b * HW + pk] * INV_TAU;
  float v = (lane < K2) ? sim : -INFINITY;
  float mx = wave_max(v);
  float e = (lane < K2) ? expf(sim - mx) : 0.f;
  float se = wave_sum(e);
  float p = e / se;
  float term = (lane < K2) ? (-p * logf(p + 1e-6f)) : 0.f;
  float en = wave_sum(term);
  if (lane == 0) ent[bm] = en;
  if (lane < K2) simc[(size_t)bm * K2 + lane] = sim;
}

__global__ void kl_kernel(const float* __restrict__ s, const int* __restrict__ anch,
                          const float* __restrict__ inv_s, const float* __restrict__ simc,
                          const int* __restrict__ sel, float* __restrict__ klpart){
  int bj = blockIdx.x;
  int b = bj >> 9, j = bj & (NSEL - 1);
  int lane = threadIdx.x;
  int m = sel[b * NSEL + j];
  int ay = anch[2 * m], ax = anch[2 * m + 1];
  int k = lane < K2 ? lane : 0;
  int dy = k / 7 - RAD, dx = k - (k / 7) * 7 - RAD;
  int pc = ay * W + ax;
  int pk = (ay + dy) * W + (ax + dx);
  const float* base = s + (size_t)b * C * HW;
  float acc = 0.f;
  #pragma unroll 4
  for (int c = 0; c < C; ++c){
    const float* row = base + (size_t)c * HW;
    acc = fmaf(row[pc], row[pk], acc);
  }
  float sim_sv = acc * inv_s[b * HW + pc] * inv_s[b * HW + pk] * INV_TAU;
  float sim_tv = (lane < K2) ? simc[((size_t)b * M + m) * K2 + lane] : -INFINITY;

  float vs = (lane < K2) ? sim_sv : -INFINITY;
  float mxs = wave_max(vs);
  float es = (lane < K2) ? expf(sim_sv - mxs) : 0.f;
  float sums = wave_sum(es);
  float ls = sim_sv - mxs - logf(sums);

  float mxt = wave_max(sim_tv);
  float et = (lane < K2) ? expf(sim_tv - mxt) : 0.f;
  float sumt = wave_sum(et);
  float lt = sim_tv - mxt - logf(sumt);

  float pt = et / sumt;
  float term = (lane < K2) ? pt * (lt - ls) : 0.f;
  float kl = wave_sum(term);
  if (lane == 0) klpart[bj] = kl;
}

extern "C" void kernel_launch(void* const* d_in, const int* in_sizes, int n_in,
                              void* d_out, int out_size, void* d_ws, size_t ws_size,
                              hipStream_t stream){
  const float* student = (const float*)d_in[0];
  const float* teacher = (const float*)d_in[1];
  const int*   anch    = (const int*)d_in[2];
  float* out = (float*)d_out;

  const size_t fbuf_elems = (size_t)B * HW * C;            // 56.6M floats
  const size_t simc_elems = (size_t)B * M * K2;
  size_t req = (fbuf_elems + simc_elems + (size_t)B * M + (size_t)B * NSEL) * sizeof(float)
             + (size_t)B * NSEL * sizeof(int);

  if (ws_size >= req){
    float* fbuf   = (float*)d_ws;                          // reused: teacher then student
    float* simc   = fbuf + fbuf_elems;
    float* ent    = simc + simc_elems;
    float* klpart = ent + (size_t)B * M;
    int*   sel    = (int*)(klpart + (size_t)B * NSEL);

    hipLaunchKernelGGL(tnorm_kernel, dim3(B * (HW / TP)), dim3(256), 0, stream, teacher, fbuf);
    hipLaunchKernelGGL(cand2_kernel, dim3(B * M), dim3(64), 0, stream, fbuf, anch, simc, ent);
    hipLaunchKernelGGL(select_kernel, dim3(B * 8), dim3(256), 0, stream, ent, sel);
    hipLaunchKernelGGL(tnorm_kernel, dim3(B * (HW / TP)), dim3(256), 0, stream, student, fbuf);
    hipLaunchKernelGGL(kl2_kernel, dim3(B * NSEL), dim3(64), 0, stream, fbuf, anch, simc, sel, klpart);
    hipLaunchKernelGGL(reduce_kernel, dim3(1), dim3(256), 0, stream, klpart, out);
  } else {
    float* ws2    = (float*)d_ws;
    float* inv_t  = ws2;
    float* inv_s  = inv_t + B * HW;
    float* ent    = inv_s + B * HW;
    float* simc   = ent + B * M;
    float* klpart = simc + simc_elems;
    int*   sel    = (int*)(klpart + (size_t)B * NSEL);

    hipLaunchKernelGGL(norms_kernel, dim3((B * HW + 255) / 256), dim3(256), 0, stream,
                       teacher, student, inv_t, inv_s);
    hipLaunchKernelGGL(cand_kernel, dim3(B * M), dim3(64), 0, stream,
                       teacher, anch, inv_t, simc, ent);
    hipLaunchKernelGGL(select_kernel, dim3(B * 8), dim3(256), 0, stream, ent, sel);
    hipLaunchKernelGGL(kl_kernel, dim3(B * NSEL), dim3(64), 0, stream,
                       student, anch, inv_s, simc, sel, klpart);
    hipLaunchKernelGGL(reduce_kernel, dim3(1), dim3(256), 0, stream, klpart, out);
  }
}